// Round 1
// 974.825 us; speedup vs baseline: 1.3526x; 1.3526x over previous
//
#include <hip/hip_runtime.h>

// B=2, H=16, L=2048, D=64. Inputs q,k,v fp32, mask int32.
// Outputs (concatenated in d_out, fp32): out (B,H,L,D) then attn (B,H,L,L).
#define L_ 2048
#define D_ 64

typedef __attribute__((ext_vector_type(8))) short bf16x8;
typedef __attribute__((ext_vector_type(4))) float f32x4;
typedef __attribute__((ext_vector_type(8))) _Float16 f16x8;

__device__ __forceinline__ unsigned short f2bf(float x) {
  union { float f; unsigned u; } v; v.f = x;
  return (unsigned short)((v.u + 0x7fffu + ((v.u >> 16) & 1u)) >> 16);
}
__device__ __forceinline__ float bf2f(unsigned short h) {
  union { unsigned u; float f; } v; v.u = ((unsigned)h) << 16; return v.f;
}

// K fp32 -> (kh, kl) bf16 split: k = kh + kl + O(2^-18 rel)
__global__ __launch_bounds__(256) void ksplit(const float* __restrict__ k,
                                              unsigned short* __restrict__ kh,
                                              unsigned short* __restrict__ kl) {
  size_t o = ((size_t)blockIdx.x * 256 + threadIdx.x) * 8;
  #pragma unroll
  for (int j = 0; j < 8; ++j) {
    float x = k[o + j];
    unsigned short h = f2bf(x);
    kh[o + j] = h;
    kl[o + j] = f2bf(x - bf2f(h));
  }
}

__device__ __forceinline__ void split4(const float4 u, float sc, bf16x8& h, bf16x8& l, int o) {
  float s; unsigned short hh;
  s = u.x * sc; hh = f2bf(s); h[o+0] = (short)hh; l[o+0] = (short)f2bf(s - bf2f(hh));
  s = u.y * sc; hh = f2bf(s); h[o+1] = (short)hh; l[o+1] = (short)f2bf(s - bf2f(hh));
  s = u.z * sc; hh = f2bf(s); h[o+2] = (short)hh; l[o+2] = (short)f2bf(s - bf2f(hh));
  s = u.w * sc; hh = f2bf(s); h[o+3] = (short)hh; l[o+3] = (short)f2bf(s - bf2f(hh));
}

// One workgroup = one (bh, 16 q-rows) tile. 256 threads = 4 waves.
// LDS ~67 KB -> 2 workgroups/CU (was 150 KB -> 1/CU).
template<bool USE_WS>
__global__ __launch_bounds__(256) void attn_fused(
    const float* __restrict__ qf, const float* __restrict__ kf,
    const unsigned short* __restrict__ khp, const unsigned short* __restrict__ klp,
    const int* __restrict__ mask, const float* __restrict__ vf,
    float* __restrict__ outp, float* __restrict__ attnp) {
  __shared__ __align__(16) _Float16 S[16][2056];   // 65792 B; row stride 4112 B (16B-aligned)
  __shared__ float red[16][17];
  __shared__ float rowM[16];
  __shared__ float rowL[16];

  const int tid = threadIdx.x;
  const int p   = blockIdx.x;
  const int wg  = ((p & 7) << 9) | (p >> 3);       // XCD-chunked swizzle: XCD x gets bh [4x,4x+4)
  const int bh  = wg >> 7;
  const int q0  = (wg & 127) << 4;
  const int b   = bh >> 4;

  const int lane = tid & 63;
  const int wave = tid >> 6;
  const int c16  = lane & 15;
  const int quad = lane >> 4;

  // ---- Q fragments in registers: q/8 = qh + ql (bf16 pair); A row = c16, k = quad*8+j ----
  bf16x8 a0h, a0l, a1h, a1l;
  {
    const float* qp = qf + ((size_t)(bh * L_ + q0 + c16)) * D_ + (quad << 3);
    float4 u0 = *(const float4*)qp;
    float4 u1 = *(const float4*)(qp + 4);
    float4 u2 = *(const float4*)(qp + 32);
    float4 u3 = *(const float4*)(qp + 36);
    split4(u0, 0.125f, a0h, a0l, 0);
    split4(u1, 0.125f, a0h, a0l, 4);
    split4(u2, 0.125f, a1h, a1l, 0);
    split4(u3, 0.125f, a1h, a1l, 4);
  }

  // ---- QK^T -> S (fp16), split-bf16 precision; fused per-lane row-max tracking ----
  float mx0 = -1e30f, mx1 = -1e30f, mx2 = -1e30f, mx3 = -1e30f;
  #pragma unroll 2
  for (int ct = 0; ct < 32; ++ct) {
    int col = (wave << 9) + (ct << 4) + c16;
    bf16x8 b0h, b1h, b0l, b1l;
    if (USE_WS) {
      const unsigned short* hp = khp + (size_t)bh * (L_ * D_) + (size_t)col * D_ + (quad << 3);
      const unsigned short* lp = klp + (size_t)bh * (L_ * D_) + (size_t)col * D_ + (quad << 3);
      b0h = *(const bf16x8*)(hp);
      b1h = *(const bf16x8*)(hp + 32);
      b0l = *(const bf16x8*)(lp);
      b1l = *(const bf16x8*)(lp + 32);
    } else {
      const float* kp = kf + (size_t)bh * (L_ * D_) + (size_t)col * D_ + (quad << 3);
      #pragma unroll
      for (int j = 0; j < 4; ++j) {
        float x0 = kp[j], x1 = kp[4 + j], x2 = kp[32 + j], x3 = kp[36 + j];
        b0h[j]     = (short)f2bf(x0); b0l[j]     = (short)f2bf(x0 - bf2f((unsigned short)b0h[j]));
        b0h[4 + j] = (short)f2bf(x1); b0l[4 + j] = (short)f2bf(x1 - bf2f((unsigned short)b0h[4 + j]));
        b1h[j]     = (short)f2bf(x2); b1l[j]     = (short)f2bf(x2 - bf2f((unsigned short)b1h[j]));
        b1h[4 + j] = (short)f2bf(x3); b1l[4 + j] = (short)f2bf(x3 - bf2f((unsigned short)b1h[4 + j]));
      }
    }
    f32x4 acc = {0.f, 0.f, 0.f, 0.f};
    acc = __builtin_amdgcn_mfma_f32_16x16x32_bf16(a0h, b0h, acc, 0, 0, 0);
    acc = __builtin_amdgcn_mfma_f32_16x16x32_bf16(a1h, b1h, acc, 0, 0, 0);
    acc = __builtin_amdgcn_mfma_f32_16x16x32_bf16(a0h, b0l, acc, 0, 0, 0);
    acc = __builtin_amdgcn_mfma_f32_16x16x32_bf16(a1h, b1l, acc, 0, 0, 0);
    acc = __builtin_amdgcn_mfma_f32_16x16x32_bf16(a0l, b0h, acc, 0, 0, 0);
    acc = __builtin_amdgcn_mfma_f32_16x16x32_bf16(a1l, b1h, acc, 0, 0, 0);
    int r0 = quad << 2;                      // D layout: col=lane&15, row=quad*4+reg
    S[r0 + 0][col] = (_Float16)acc[0];
    S[r0 + 1][col] = (_Float16)acc[1];
    S[r0 + 2][col] = (_Float16)acc[2];
    S[r0 + 3][col] = (_Float16)acc[3];
    mx0 = fmaxf(mx0, acc[0]); mx1 = fmaxf(mx1, acc[1]);
    mx2 = fmaxf(mx2, acc[2]); mx3 = fmaxf(mx3, acc[3]);
  }
  // cross-lane row-max within each 16-lane quad group (rows quad*4+g)
  #pragma unroll
  for (int off = 1; off < 16; off <<= 1) {
    mx0 = fmaxf(mx0, __shfl_xor(mx0, off));
    mx1 = fmaxf(mx1, __shfl_xor(mx1, off));
    mx2 = fmaxf(mx2, __shfl_xor(mx2, off));
    mx3 = fmaxf(mx3, __shfl_xor(mx3, off));
  }
  if (c16 == 0) {
    int r0 = quad << 2;
    red[r0 + 0][wave] = mx0;
    red[r0 + 1][wave] = mx1;
    red[r0 + 2][wave] = mx2;
    red[r0 + 3][wave] = mx3;
  }
  __syncthreads();
  if (tid < 16) {
    rowM[tid] = fmaxf(fmaxf(red[tid][0], red[tid][1]), fmaxf(red[tid][2], red[tid][3]));
  }
  __syncthreads();

  const int row = tid >> 4;
  const int sub = tid & 15;

  // ---- e = mask ? exp(s-m) : 0 ; store fp16; partial row sums ----
  {
    const float m = rowM[row];
    const int* mrow = mask + ((size_t)(b * L_ + q0 + row)) * L_;
    float l = 0.f;
    #pragma unroll 4
    for (int t = 0; t < 16; ++t) {
      int c = (sub + (t << 4)) << 3;
      f16x8 s8 = *(const f16x8*)&S[row][c];
      int4 m0 = *(const int4*)(mrow + c);
      int4 m1 = *(const int4*)(mrow + c + 4);
      float e0 = m0.x ? __expf((float)s8[0] - m) : 0.f;
      float e1 = m0.y ? __expf((float)s8[1] - m) : 0.f;
      float e2 = m0.z ? __expf((float)s8[2] - m) : 0.f;
      float e3 = m0.w ? __expf((float)s8[3] - m) : 0.f;
      float e4 = m1.x ? __expf((float)s8[4] - m) : 0.f;
      float e5 = m1.y ? __expf((float)s8[5] - m) : 0.f;
      float e6 = m1.z ? __expf((float)s8[6] - m) : 0.f;
      float e7 = m1.w ? __expf((float)s8[7] - m) : 0.f;
      f16x8 o8;
      o8[0] = (_Float16)e0; o8[1] = (_Float16)e1; o8[2] = (_Float16)e2; o8[3] = (_Float16)e3;
      o8[4] = (_Float16)e4; o8[5] = (_Float16)e5; o8[6] = (_Float16)e6; o8[7] = (_Float16)e7;
      *(f16x8*)&S[row][c] = o8;
      l += ((e0 + e1) + (e2 + e3)) + ((e4 + e5) + (e6 + e7));
    }
    red[row][sub] = l;
  }
  __syncthreads();
  if (tid < 16) {
    float l = 0.f;
    #pragma unroll
    for (int i = 0; i < 16; ++i) l += red[tid][i];
    rowL[tid] = (l > 0.f) ? (1.f / l) : 0.f;
  }
  __syncthreads();

  // ---- attn = e * inv -> fp32 nontemporal stores (coalesced; drain during PV) ----
  {
    float* ab = attnp + ((size_t)(bh * L_ + q0)) * L_;
    #pragma unroll 2
    for (int r = 0; r < 16; ++r) {
      const float inv = rowL[r];
      f16x8 e8 = *(const f16x8*)&S[r][tid << 3];
      f32x4 p0 = { (float)e8[0] * inv, (float)e8[1] * inv, (float)e8[2] * inv, (float)e8[3] * inv };
      f32x4 p1 = { (float)e8[4] * inv, (float)e8[5] * inv, (float)e8[6] * inv, (float)e8[7] * inv };
      float* dst = ab + (size_t)r * L_ + (tid << 3);
      __builtin_nontemporal_store(p0, (f32x4*)dst);
      __builtin_nontemporal_store(p1, (f32x4*)(dst + 4));
    }
  }

  // ---- PV: O = P*V, split-D across waves (wave owns 16 dims, full K sweep) ----
  // A = raw fp16 e from LDS (no repack); inv folded into output scale per row.
  {
    const float* vb = vf + (size_t)bh * (L_ * D_);
    const int dcol = (wave << 4) + c16;
    f32x4 o = {0.f, 0.f, 0.f, 0.f};
    #pragma unroll 2
    for (int kt = 0; kt < 64; ++kt) {
      int k0 = kt << 5;
      f16x8 af = *(const f16x8*)&S[c16][k0 + (quad << 3)];
      const float* vp = vb + (size_t)(k0 + (quad << 3)) * D_ + dcol;
      f16x8 bv;
      #pragma unroll
      for (int j = 0; j < 8; ++j) bv[j] = (_Float16)vp[(size_t)j * D_];
      o = __builtin_amdgcn_mfma_f32_16x16x32_f16(af, bv, o, 0, 0, 0);
    }
    const int r0 = quad << 2;
    float* ob = outp + ((size_t)(bh * L_ + q0)) * D_;
    #pragma unroll
    for (int g = 0; g < 4; ++g) {
      float val = o[g] * rowL[r0 + g];
      __builtin_nontemporal_store(val, ob + (size_t)(r0 + g) * D_ + dcol);
    }
  }
}

extern "C" void kernel_launch(void* const* d_in, const int* in_sizes, int n_in,
                              void* d_out, int out_size, void* d_ws, size_t ws_size,
                              hipStream_t stream) {
  const float* q = (const float*)d_in[0];
  const float* k = (const float*)d_in[1];
  const float* v = (const float*)d_in[2];
  const int* mask = (const int*)d_in[3];
  float* outp  = (float*)d_out;                      // out: 4194304 f32
  float* attnp = outp + (size_t)4194304;             // attn: 134217728 f32

  if (ws_size >= (size_t)16777216) {                 // kh + kl, 8 MB each
    unsigned short* kh = (unsigned short*)d_ws;
    unsigned short* kl = kh + (size_t)4194304;
    ksplit<<<2048, 256, 0, stream>>>(k, kh, kl);
    attn_fused<true><<<4096, 256, 0, stream>>>(q, k, kh, kl, mask, v, outp, attnp);
  } else {
    attn_fused<false><<<4096, 256, 0, stream>>>(q, k, nullptr, nullptr, mask, v, outp, attnp);
  }
}

// Round 2
// 942.416 us; speedup vs baseline: 1.3991x; 1.0344x over previous
//
#include <hip/hip_runtime.h>

// B=2, H=16, L=2048, D=64. Inputs q,k,v fp32, mask int32.
// Outputs (concatenated in d_out, fp32): out (B,H,L,D) then attn (B,H,L,L).
#define L_ 2048
#define D_ 64

typedef __attribute__((ext_vector_type(8))) short bf16x8;
typedef __attribute__((ext_vector_type(4))) float f32x4;
typedef __attribute__((ext_vector_type(8))) _Float16 f16x8;

__device__ __forceinline__ unsigned short f2bf(float x) {
  union { float f; unsigned u; } v; v.f = x;
  return (unsigned short)((v.u + 0x7fffu + ((v.u >> 16) & 1u)) >> 16);
}
__device__ __forceinline__ float bf2f(unsigned short h) {
  union { unsigned u; float f; } v; v.u = ((unsigned)h) << 16; return v.f;
}

// K fp32 -> (kh, kl) bf16 split: k = kh + kl + O(2^-18 rel)
__global__ __launch_bounds__(256) void ksplit(const float* __restrict__ k,
                                              unsigned short* __restrict__ kh,
                                              unsigned short* __restrict__ kl) {
  size_t o = ((size_t)blockIdx.x * 256 + threadIdx.x) * 8;
  #pragma unroll
  for (int j = 0; j < 8; ++j) {
    float x = k[o + j];
    unsigned short h = f2bf(x);
    kh[o + j] = h;
    kl[o + j] = f2bf(x - bf2f(h));
  }
}

// V fp32 [bh][k][d] -> Vt fp16 [bh][d][k]  (PV B-operand becomes one 16B load/MFMA)
__global__ __launch_bounds__(256) void vtrans(const float* __restrict__ v,
                                              _Float16* __restrict__ vt) {
  __shared__ _Float16 T[64][72];
  const int blk = blockIdx.x;            // 32 bh * 32 ktiles
  const int bh  = blk >> 5;
  const int k0  = (blk & 31) << 6;
  const int tid = threadIdx.x;
  const float* vb = v + (size_t)bh * (L_ * D_) + (size_t)k0 * D_;
  const int r = tid >> 4, c4 = (tid & 15) << 2;
  #pragma unroll
  for (int p = 0; p < 4; ++p) {
    float4 u = *(const float4*)(vb + (size_t)(r + p * 16) * D_ + c4);
    T[r + p * 16][c4 + 0] = (_Float16)u.x;
    T[r + p * 16][c4 + 1] = (_Float16)u.y;
    T[r + p * 16][c4 + 2] = (_Float16)u.z;
    T[r + p * 16][c4 + 3] = (_Float16)u.w;
  }
  __syncthreads();
  _Float16* vo = vt + (size_t)bh * (D_ * L_);
  const int d = tid >> 2, kk = (tid & 3) << 4;
  f16x8 w0, w1;
  #pragma unroll
  for (int j = 0; j < 8; ++j) { w0[j] = T[kk + j][d]; w1[j] = T[kk + 8 + j][d]; }
  *(f16x8*)(vo + (size_t)d * L_ + k0 + kk) = w0;
  *(f16x8*)(vo + (size_t)d * L_ + k0 + kk + 8) = w1;
}

__device__ __forceinline__ void split4(const float4 u, float sc, bf16x8& h, bf16x8& l, int o) {
  float s; unsigned short hh;
  s = u.x * sc; hh = f2bf(s); h[o+0] = (short)hh; l[o+0] = (short)f2bf(s - bf2f(hh));
  s = u.y * sc; hh = f2bf(s); h[o+1] = (short)hh; l[o+1] = (short)f2bf(s - bf2f(hh));
  s = u.z * sc; hh = f2bf(s); h[o+2] = (short)hh; l[o+2] = (short)f2bf(s - bf2f(hh));
  s = u.w * sc; hh = f2bf(s); h[o+3] = (short)hh; l[o+3] = (short)f2bf(s - bf2f(hh));
}

// One workgroup = one (bh, 16 q-rows) tile. 256 threads = 4 waves. ~67 KB LDS -> 2 wg/CU.
template<bool USE_WS, bool USE_VT>
__global__ __launch_bounds__(256) void attn_fused(
    const float* __restrict__ qf, const float* __restrict__ kf,
    const unsigned short* __restrict__ khp, const unsigned short* __restrict__ klp,
    const int* __restrict__ mask, const float* __restrict__ vf,
    const _Float16* __restrict__ vtp_g,
    float* __restrict__ outp, float* __restrict__ attnp) {
  __shared__ __align__(16) _Float16 S[16][2056];   // 65792 B; row stride 4112 B
  __shared__ float red[16][17];
  __shared__ float rowM[16];
  __shared__ float rowL[16];

  const int tid = threadIdx.x;
  const int p   = blockIdx.x;
  const int wg  = ((p & 7) << 9) | (p >> 3);       // XCD-chunked swizzle
  const int bh  = wg >> 7;
  const int q0  = (wg & 127) << 4;
  const int b   = bh >> 4;

  const int lane = tid & 63;
  const int wave = tid >> 6;
  const int c16  = lane & 15;
  const int quad = lane >> 4;

  // ---- Q fragments in registers: q/8 = qh + ql (bf16 pair) ----
  bf16x8 a0h, a0l, a1h, a1l;
  {
    const float* qp = qf + ((size_t)(bh * L_ + q0 + c16)) * D_ + (quad << 3);
    float4 u0 = *(const float4*)qp;
    float4 u1 = *(const float4*)(qp + 4);
    float4 u2 = *(const float4*)(qp + 32);
    float4 u3 = *(const float4*)(qp + 36);
    split4(u0, 0.125f, a0h, a0l, 0);
    split4(u1, 0.125f, a0h, a0l, 4);
    split4(u2, 0.125f, a1h, a1l, 0);
    split4(u3, 0.125f, a1h, a1l, 4);
  }

  // ---- QK^T -> S (fp16), split-bf16 precision; fused per-lane row-max ----
  float mx0 = -1e30f, mx1 = -1e30f, mx2 = -1e30f, mx3 = -1e30f;
  #pragma unroll 2
  for (int ct = 0; ct < 32; ++ct) {
    int col = (wave << 9) + (ct << 4) + c16;
    bf16x8 b0h, b1h, b0l, b1l;
    if (USE_WS) {
      const unsigned short* hp = khp + (size_t)bh * (L_ * D_) + (size_t)col * D_ + (quad << 3);
      const unsigned short* lp = klp + (size_t)bh * (L_ * D_) + (size_t)col * D_ + (quad << 3);
      b0h = *(const bf16x8*)(hp);
      b1h = *(const bf16x8*)(hp + 32);
      b0l = *(const bf16x8*)(lp);
      b1l = *(const bf16x8*)(lp + 32);
    } else {
      const float* kp = kf + (size_t)bh * (L_ * D_) + (size_t)col * D_ + (quad << 3);
      #pragma unroll
      for (int j = 0; j < 4; ++j) {
        float x0 = kp[j], x1 = kp[4 + j], x2 = kp[32 + j], x3 = kp[36 + j];
        b0h[j]     = (short)f2bf(x0); b0l[j]     = (short)f2bf(x0 - bf2f((unsigned short)b0h[j]));
        b0h[4 + j] = (short)f2bf(x1); b0l[4 + j] = (short)f2bf(x1 - bf2f((unsigned short)b0h[4 + j]));
        b1h[j]     = (short)f2bf(x2); b1l[j]     = (short)f2bf(x2 - bf2f((unsigned short)b1h[j]));
        b1h[4 + j] = (short)f2bf(x3); b1l[4 + j] = (short)f2bf(x3 - bf2f((unsigned short)b1h[4 + j]));
      }
    }
    f32x4 acc = {0.f, 0.f, 0.f, 0.f};
    acc = __builtin_amdgcn_mfma_f32_16x16x32_bf16(a0h, b0h, acc, 0, 0, 0);
    acc = __builtin_amdgcn_mfma_f32_16x16x32_bf16(a1h, b1h, acc, 0, 0, 0);
    acc = __builtin_amdgcn_mfma_f32_16x16x32_bf16(a0h, b0l, acc, 0, 0, 0);
    acc = __builtin_amdgcn_mfma_f32_16x16x32_bf16(a1h, b1l, acc, 0, 0, 0);
    acc = __builtin_amdgcn_mfma_f32_16x16x32_bf16(a0l, b0h, acc, 0, 0, 0);
    acc = __builtin_amdgcn_mfma_f32_16x16x32_bf16(a1l, b1h, acc, 0, 0, 0);
    int r0 = quad << 2;                      // D layout: col=lane&15, row=quad*4+reg
    S[r0 + 0][col] = (_Float16)acc[0];
    S[r0 + 1][col] = (_Float16)acc[1];
    S[r0 + 2][col] = (_Float16)acc[2];
    S[r0 + 3][col] = (_Float16)acc[3];
    mx0 = fmaxf(mx0, acc[0]); mx1 = fmaxf(mx1, acc[1]);
    mx2 = fmaxf(mx2, acc[2]); mx3 = fmaxf(mx3, acc[3]);
  }
  #pragma unroll
  for (int off = 1; off < 16; off <<= 1) {
    mx0 = fmaxf(mx0, __shfl_xor(mx0, off));
    mx1 = fmaxf(mx1, __shfl_xor(mx1, off));
    mx2 = fmaxf(mx2, __shfl_xor(mx2, off));
    mx3 = fmaxf(mx3, __shfl_xor(mx3, off));
  }
  if (c16 == 0) {
    int r0 = quad << 2;
    red[r0 + 0][wave] = mx0;
    red[r0 + 1][wave] = mx1;
    red[r0 + 2][wave] = mx2;
    red[r0 + 3][wave] = mx3;
  }
  __syncthreads();
  if (tid < 16) {
    rowM[tid] = fmaxf(fmaxf(red[tid][0], red[tid][1]), fmaxf(red[tid][2], red[tid][3]));
  }
  __syncthreads();

  const int row = tid >> 4;
  const int sub = tid & 15;

  // ---- e = mask ? exp(s-m) : 0 ; store fp16; partial row sums ----
  {
    const float m = rowM[row];
    const int* mrow = mask + ((size_t)(b * L_ + q0 + row)) * L_;
    float l = 0.f;
    #pragma unroll 4
    for (int t = 0; t < 16; ++t) {
      int c = (sub + (t << 4)) << 3;
      f16x8 s8 = *(const f16x8*)&S[row][c];
      int4 m0 = *(const int4*)(mrow + c);
      int4 m1 = *(const int4*)(mrow + c + 4);
      float e0 = m0.x ? __expf((float)s8[0] - m) : 0.f;
      float e1 = m0.y ? __expf((float)s8[1] - m) : 0.f;
      float e2 = m0.z ? __expf((float)s8[2] - m) : 0.f;
      float e3 = m0.w ? __expf((float)s8[3] - m) : 0.f;
      float e4 = m1.x ? __expf((float)s8[4] - m) : 0.f;
      float e5 = m1.y ? __expf((float)s8[5] - m) : 0.f;
      float e6 = m1.z ? __expf((float)s8[6] - m) : 0.f;
      float e7 = m1.w ? __expf((float)s8[7] - m) : 0.f;
      f16x8 o8;
      o8[0] = (_Float16)e0; o8[1] = (_Float16)e1; o8[2] = (_Float16)e2; o8[3] = (_Float16)e3;
      o8[4] = (_Float16)e4; o8[5] = (_Float16)e5; o8[6] = (_Float16)e6; o8[7] = (_Float16)e7;
      *(f16x8*)&S[row][c] = o8;
      l += ((e0 + e1) + (e2 + e3)) + ((e4 + e5) + (e6 + e7));
    }
    red[row][sub] = l;
  }
  __syncthreads();
  if (tid < 16) {
    float l = 0.f;
    #pragma unroll
    for (int i = 0; i < 16; ++i) l += red[tid][i];
    rowL[tid] = (l > 0.f) ? (1.f / l) : 0.f;
  }
  __syncthreads();

  // ---- attn = e * inv -> fp32 nontemporal stores ----
  {
    float* ab = attnp + ((size_t)(bh * L_ + q0)) * L_;
    #pragma unroll 2
    for (int r = 0; r < 16; ++r) {
      const float inv = rowL[r];
      f16x8 e8 = *(const f16x8*)&S[r][tid << 3];
      f32x4 p0 = { (float)e8[0] * inv, (float)e8[1] * inv, (float)e8[2] * inv, (float)e8[3] * inv };
      f32x4 p1 = { (float)e8[4] * inv, (float)e8[5] * inv, (float)e8[6] * inv, (float)e8[7] * inv };
      float* dst = ab + (size_t)r * L_ + (tid << 3);
      __builtin_nontemporal_store(p0, (f32x4*)dst);
      __builtin_nontemporal_store(p1, (f32x4*)(dst + 4));
    }
  }

  // ---- PV: O = P*V, split-D across waves; B from Vt (one 16B load per MFMA) ----
  {
    const int dcol = (wave << 4) + c16;
    f32x4 o = {0.f, 0.f, 0.f, 0.f};
    if (USE_VT) {
      const _Float16* vrow = vtp_g + (size_t)bh * (D_ * L_) + (size_t)dcol * L_ + (quad << 3);
      #pragma unroll 4
      for (int kt = 0; kt < 64; ++kt) {
        int k0 = kt << 5;
        f16x8 af = *(const f16x8*)&S[c16][k0 + (quad << 3)];
        f16x8 bv = *(const f16x8*)(vrow + k0);
        o = __builtin_amdgcn_mfma_f32_16x16x32_f16(af, bv, o, 0, 0, 0);
      }
    } else {
      const float* vb = vf + (size_t)bh * (L_ * D_);
      #pragma unroll 2
      for (int kt = 0; kt < 64; ++kt) {
        int k0 = kt << 5;
        f16x8 af = *(const f16x8*)&S[c16][k0 + (quad << 3)];
        const float* vp = vb + (size_t)(k0 + (quad << 3)) * D_ + dcol;
        f16x8 bv;
        #pragma unroll
        for (int j = 0; j < 8; ++j) bv[j] = (_Float16)vp[(size_t)j * D_];
        o = __builtin_amdgcn_mfma_f32_16x16x32_f16(af, bv, o, 0, 0, 0);
      }
    }
    const int r0 = quad << 2;
    float* ob = outp + ((size_t)(bh * L_ + q0)) * D_;
    #pragma unroll
    for (int g = 0; g < 4; ++g) {
      float val = o[g] * rowL[r0 + g];
      __builtin_nontemporal_store(val, ob + (size_t)(r0 + g) * D_ + dcol);
    }
  }
}

extern "C" void kernel_launch(void* const* d_in, const int* in_sizes, int n_in,
                              void* d_out, int out_size, void* d_ws, size_t ws_size,
                              hipStream_t stream) {
  const float* q = (const float*)d_in[0];
  const float* k = (const float*)d_in[1];
  const float* v = (const float*)d_in[2];
  const int* mask = (const int*)d_in[3];
  float* outp  = (float*)d_out;                      // out: 4194304 f32
  float* attnp = outp + (size_t)4194304;             // attn: 134217728 f32

  if (ws_size >= (size_t)25165824) {                 // kh(8MB) + kl(8MB) + vt(8MB)
    unsigned short* kh = (unsigned short*)d_ws;
    unsigned short* kl = kh + (size_t)4194304;
    _Float16* vt = (_Float16*)(kl + (size_t)4194304);
    ksplit<<<2048, 256, 0, stream>>>(k, kh, kl);
    vtrans<<<1024, 256, 0, stream>>>(v, vt);
    attn_fused<true, true><<<4096, 256, 0, stream>>>(q, k, kh, kl, mask, v, vt, outp, attnp);
  } else if (ws_size >= (size_t)16777216) {          // kh + kl only
    unsigned short* kh = (unsigned short*)d_ws;
    unsigned short* kl = kh + (size_t)4194304;
    ksplit<<<2048, 256, 0, stream>>>(k, kh, kl);
    attn_fused<true, false><<<4096, 256, 0, stream>>>(q, k, kh, kl, mask, v, nullptr, outp, attnp);
  } else {
    attn_fused<false, false><<<4096, 256, 0, stream>>>(q, k, nullptr, nullptr, mask, v, nullptr, outp, attnp);
  }
}